// Round 9
// baseline (263.046 us; speedup 1.0000x reference)
//
#include <hip/hip_runtime.h>
#include <stdint.h>

#define BATCH 2
#define SEQ   1024
#define DIM_  1024
#define DS_   16
#define DI_   2048
#define NTOK  (BATCH*SEQ)   // 2048
#define NSEG  32
#define LSEG  (SEQ/NSEG)    // 32

typedef unsigned short u16;
using s16x8 = __attribute__((ext_vector_type(8))) short;
using f32x4 = __attribute__((ext_vector_type(4))) float;
using u16x4 = __attribute__((ext_vector_type(4))) unsigned short;
using u16x8 = __attribute__((ext_vector_type(8))) unsigned short;

__device__ __forceinline__ float bf2f(u16 u) {
  union { unsigned int i; float f; } c; c.i = ((unsigned int)u) << 16; return c.f;
}
__device__ __forceinline__ u16 f2bf(float f) {
  union { float f; unsigned int i; } c; c.f = f;
  unsigned int r = c.i + 0x7fffu + ((c.i >> 16) & 1u);
  return (u16)(r >> 16);
}
__device__ __forceinline__ float softplus_f(float x) {
  return (x > 15.f) ? x : __logf(1.f + __expf(x));
}
__device__ __forceinline__ u16x4 f4_to_bf(float4 v) {
  u16x4 r; r[0] = f2bf(v.x); r[1] = f2bf(v.y); r[2] = f2bf(v.z); r[3] = f2bf(v.w);
  return r;
}

// ---------------- merged: weight conversions + LayerNorm (+ counter zero) ----------------
#define N4_INW  (2 * DI_ * DIM_ / 4)   // 1048576
#define N4_OUTW (DIM_ * DI_ / 4)       // 524288
#define CVT_BLOCKS ((N4_INW + N4_OUTW + 32768) / 256)   // 6272
__global__ __launch_bounds__(256) void cvt_ln_kernel(const float* __restrict__ in_w,
    const float* __restrict__ out_w, const float* __restrict__ xproj_w,
    const float* __restrict__ x, const float* __restrict__ nw,
    const float* __restrict__ nb, u16* __restrict__ in_w_bf,
    u16* __restrict__ out_w_bf, u16* __restrict__ xpw_bf, u16* __restrict__ xn,
    unsigned int* __restrict__ cnt) {
  int tid = threadIdx.x;
  if (blockIdx.x == 0 && tid < NTOK / 64) cnt[tid] = 0;   // split-K finish counters
  if (blockIdx.x < CVT_BLOCKS) {
    int i = blockIdx.x * 256 + tid;
    if (i < N4_INW) {
      ((u16x4*)in_w_bf)[i] = f4_to_bf(((const float4*)in_w)[i]);
    } else if (i < N4_INW + N4_OUTW) {
      int j = i - N4_INW;
      ((u16x4*)out_w_bf)[j] = f4_to_bf(((const float4*)out_w)[j]);
    } else {
      int j = i - (N4_INW + N4_OUTW);
      if (j >= 32768) return;
      int p = (j * 4) >> 11;
      u16x4 r;
      if (p < 33) r = f4_to_bf(((const float4*)xproj_w)[j]);
      else { r[0] = 0; r[1] = 0; r[2] = 0; r[3] = 0; }
      ((u16x4*)xpw_bf)[j] = r;
    }
    return;
  }
  // LayerNorm branch
  int t = blockIdx.x - CVT_BLOCKS;
  const float* row = x + (size_t)t * DIM_;
  float4 v = ((const float4*)row)[tid];
  float f[4] = {v.x, v.y, v.z, v.w};
  float s = 0.f, sq = 0.f;
#pragma unroll
  for (int j = 0; j < 4; j++) { s += f[j]; sq += f[j] * f[j]; }
#pragma unroll
  for (int m = 1; m < 64; m <<= 1) { s += __shfl_xor(s, m); sq += __shfl_xor(sq, m); }
  __shared__ float rs_[4], rq_[4];
  int wv = tid >> 6;
  if ((tid & 63) == 0) { rs_[wv] = s; rq_[wv] = sq; }
  __syncthreads();
  s = rs_[0] + rs_[1] + rs_[2] + rs_[3];
  sq = rq_[0] + rq_[1] + rq_[2] + rq_[3];
  float mu = s * (1.0f / DIM_);
  float var = sq * (1.0f / DIM_) - mu * mu;
  float rstd = rsqrtf(var + 1e-5f);
  float4 wn = ((const float4*)nw)[tid];
  float4 bn = ((const float4*)nb)[tid];
  u16x4 o;
  o[0] = f2bf((f[0] - mu) * rstd * wn.x + bn.x);
  o[1] = f2bf((f[1] - mu) * rstd * wn.y + bn.y);
  o[2] = f2bf((f[2] - mu) * rstd * wn.z + bn.z);
  o[3] = f2bf((f[3] - mu) * rstd * wn.w + bn.w);
  *(u16x4*)(xn + (size_t)t * DIM_ + tid * 4) = o;
}

// ---------------- GEMM C = A(M,K)bf16 * W(N,K)^T bf16, f32 acc ----------------
template<int TBM, int TBN, int BK, typename OUT, int EPI, int KSPLIT = 1, int SWZ = 0>
__global__ __launch_bounds__(256) void gemm_bt(const u16* __restrict__ A,
    const u16* __restrict__ Wt, OUT* __restrict__ C, const float* __restrict__ X,
    int M, int N, int K) {
  constexpr int LDT = BK + 8;
  constexpr int TPR = BK / 8;
  constexpr int RPP = 256 / TPR;
  constexpr int ALn = TBM / RPP;
  constexpr int BLn = TBN / RPP;
  constexpr int KK = BK / 32;
  constexpr int WM = TBM / 2, WN = TBN / 2;
  constexpr int MI = WM / 16, NJ = WN / 16;
  __shared__ __align__(16) u16 sA[TBM * LDT];
  __shared__ __align__(16) u16 sB[TBN * LDT];
  const int tid = threadIdx.x;
  const int lane = tid & 63, wv = tid >> 6;
  const int wm = (wv >> 1) * WM, wn = (wv & 1) * WN;
  const int bxl = SWZ ? ((blockIdx.x & 7) * (gridDim.x >> 3) + (blockIdx.x >> 3))
                      : blockIdx.x;
  const int bm0 = blockIdx.y * TBM, bn0 = bxl * TBN;
  const int q = lane >> 4, r16 = lane & 15;
  const int srow = tid / TPR, scol = (tid % TPR) * 8;
  const int kc = K / KSPLIT;
  const int k0 = (KSPLIT > 1) ? blockIdx.z * kc : 0;
  const int kend = k0 + kc;

  f32x4 acc[MI][NJ];
#pragma unroll
  for (int i = 0; i < MI; i++)
#pragma unroll
    for (int j = 0; j < NJ; j++)
#pragma unroll
      for (int r = 0; r < 4; r++) acc[i][j][r] = 0.f;

  const u16* Ag = A + (size_t)bm0 * K + scol + k0;
  const u16* Wg = Wt + (size_t)bn0 * K + scol + k0;
  s16x8 ra[ALn], rb[BLn];
#pragma unroll
  for (int i = 0; i < ALn; i++) ra[i] = *(const s16x8*)(Ag + (size_t)(srow + i * RPP) * K);
#pragma unroll
  for (int i = 0; i < BLn; i++) rb[i] = *(const s16x8*)(Wg + (size_t)(srow + i * RPP) * K);

  for (int kt = k0; kt < kend; kt += BK) {
    __syncthreads();
#pragma unroll
    for (int i = 0; i < ALn; i++) *(s16x8*)&sA[(srow + i * RPP) * LDT + scol] = ra[i];
#pragma unroll
    for (int i = 0; i < BLn; i++) *(s16x8*)&sB[(srow + i * RPP) * LDT + scol] = rb[i];
    __syncthreads();
    int kn = kt + BK - k0;
    if (kn < kc) {
#pragma unroll
      for (int i = 0; i < ALn; i++) ra[i] = *(const s16x8*)(Ag + (size_t)(srow + i * RPP) * K + kn);
#pragma unroll
      for (int i = 0; i < BLn; i++) rb[i] = *(const s16x8*)(Wg + (size_t)(srow + i * RPP) * K + kn);
    }
#pragma unroll
    for (int kk = 0; kk < KK; kk++) {
      s16x8 fa[MI], fb[NJ];
#pragma unroll
      for (int i = 0; i < MI; i++)
        fa[i] = *(const s16x8*)&sA[(wm + i * 16 + r16) * LDT + kk * 32 + q * 8];
#pragma unroll
      for (int j = 0; j < NJ; j++)
        fb[j] = *(const s16x8*)&sB[(wn + j * 16 + r16) * LDT + kk * 32 + q * 8];
#pragma unroll
      for (int i = 0; i < MI; i++)
#pragma unroll
        for (int j = 0; j < NJ; j++)
          acc[i][j] = __builtin_amdgcn_mfma_f32_16x16x32_bf16(fa[i], fb[j], acc[i][j], 0, 0, 0);
    }
  }
  OUT* Cz = C + ((KSPLIT > 1) ? (size_t)blockIdx.z * M * N : 0);
#pragma unroll
  for (int i = 0; i < MI; i++)
#pragma unroll
    for (int j = 0; j < NJ; j++) {
      int row0 = bm0 + wm + i * 16 + q * 4;
      int col = bn0 + wn + j * 16 + r16;
#pragma unroll
      for (int r = 0; r < 4; r++) {
        size_t off = (size_t)(row0 + r) * N + col;
        float v = acc[i][j][r];
        if constexpr (EPI == 1) v += X[off];
        if constexpr (sizeof(OUT) == 2) Cz[off] = f2bf(v);
        else                            Cz[off] = v;
      }
    }
}

// ---------------- fused conv+silu + x_proj split-K GEMM + last-block finish ----------------
// 8 z-blocks per 64-token group.  Last z-block (device atomic) reduces xp_part,
// writes bc and delta (softplus) -> dlt.  delta goes to a SEPARATE buffer (not xz)
// to avoid racing other groups' conv taps on xz boundary rows.
__global__ __launch_bounds__(256) void convxp_gemm(const u16* __restrict__ xz,
    const float* __restrict__ cw, const float* __restrict__ cb,
    const u16* __restrict__ Wt, float* __restrict__ C, u16* __restrict__ xc,
    const float* __restrict__ dtw, const float* __restrict__ dtb,
    float* __restrict__ bc, u16* __restrict__ dlt, unsigned int* __restrict__ cnt) {
  constexpr int BK = 32, LDT = BK + 8;
  constexpr int WM = 32, WN = 32, MI = 2, NJ = 2;
  constexpr int K = DI_, Nn = 64;
  __shared__ __align__(16) u16 sA[64 * LDT];
  __shared__ __align__(16) u16 sB[64 * LDT];
  const int tid = threadIdx.x;
  const int lane = tid & 63, wv = tid >> 6;
  const int wm = (wv >> 1) * WM, wn = (wv & 1) * WN;
  const int bm0 = blockIdx.y * 64;
  const int q = lane >> 4, r16 = lane & 15;
  const int srow = tid >> 2, scol = (tid & 3) * 8;   // TPR=4, RPP=64
  const int kc = K / 8;
  const int k0 = blockIdx.z * kc;

  f32x4 acc[MI][NJ];
#pragma unroll
  for (int i = 0; i < MI; i++)
#pragma unroll
    for (int j = 0; j < NJ; j++)
#pragma unroll
      for (int r = 0; r < 4; r++) acc[i][j][r] = 0.f;

  const int tm = bm0 + srow;
  const int l = tm & (SEQ - 1);
  const u16* Wg = Wt + (size_t)srow * K + scol + k0;

  auto conv8 = [&](int kt) -> s16x8 {
    int ch = k0 + kt + scol;
    float a[8];
    float4 cb0 = *(const float4*)(cb + ch);
    float4 cb1 = *(const float4*)(cb + ch + 4);
    a[0] = cb0.x; a[1] = cb0.y; a[2] = cb0.z; a[3] = cb0.w;
    a[4] = cb1.x; a[5] = cb1.y; a[6] = cb1.z; a[7] = cb1.w;
#pragma unroll
    for (int k = 0; k < 4; k++) {
      if (l - 3 + k >= 0) {
        u16x8 v = *(const u16x8*)(xz + (size_t)(tm - 3 + k) * (2 * DI_) + ch);
#pragma unroll
        for (int j = 0; j < 8; j++) {
          float4 wj = ((const float4*)cw)[ch + j];
          float wk = (k == 0) ? wj.x : (k == 1) ? wj.y : (k == 2) ? wj.z : wj.w;
          a[j] = fmaf(bf2f(v[j]), wk, a[j]);
        }
      }
    }
    u16x8 o;
#pragma unroll
    for (int j = 0; j < 8; j++) {
      float s = a[j] / (1.0f + __expf(-a[j]));
      o[j] = f2bf(s);
    }
    *(u16x8*)(xc + (size_t)tm * DI_ + ch) = o;
    return *(s16x8*)&o;
  };

  s16x8 ra = conv8(0);
  s16x8 rb = *(const s16x8*)Wg;

  for (int kt = 0; kt < kc; kt += BK) {
    __syncthreads();
    *(s16x8*)&sA[srow * LDT + scol] = ra;
    *(s16x8*)&sB[srow * LDT + scol] = rb;
    __syncthreads();
    int kn = kt + BK;
    if (kn < kc) {
      ra = conv8(kn);
      rb = *(const s16x8*)(Wg + kn);
    }
    {
      s16x8 fa[MI], fb[NJ];
#pragma unroll
      for (int i = 0; i < MI; i++)
        fa[i] = *(const s16x8*)&sA[(wm + i * 16 + r16) * LDT + q * 8];
#pragma unroll
      for (int j = 0; j < NJ; j++)
        fb[j] = *(const s16x8*)&sB[(wn + j * 16 + r16) * LDT + q * 8];
#pragma unroll
      for (int i = 0; i < MI; i++)
#pragma unroll
        for (int j = 0; j < NJ; j++)
          acc[i][j] = __builtin_amdgcn_mfma_f32_16x16x32_bf16(fa[i], fb[j], acc[i][j], 0, 0, 0);
    }
  }
  float* Cz = C + (size_t)blockIdx.z * NTOK * Nn;
#pragma unroll
  for (int i = 0; i < MI; i++)
#pragma unroll
    for (int j = 0; j < NJ; j++) {
      int row0 = bm0 + wm + i * 16 + q * 4;
      int col = wn + j * 16 + r16;
#pragma unroll
      for (int r = 0; r < 4; r++)
        Cz[(size_t)(row0 + r) * Nn + col] = acc[i][j][r];
    }

  // ---- last-block finish (replaces xp_finish kernel) ----
  __shared__ unsigned int isLast;
  __threadfence();                      // release: xp_part writes visible
  if (tid == 0) {
    unsigned int old = atomicAdd(&cnt[blockIdx.y], 1u);
    isLast = (old == 7u) ? 1u : 0u;
  }
  __syncthreads();
  if (!isLast) return;
  __threadfence();                      // acquire: see all 8 chunks

  __shared__ float xps[64][33];
  for (int idx = tid; idx < 64 * 33; idx += 256) {
    int t = idx / 33, c = idx - t * 33;
    float s = 0.f;
#pragma unroll
    for (int k = 0; k < 8; k++)
      s += C[(size_t)k * NTOK * 64 + (size_t)(bm0 + t) * 64 + c];
    xps[t][c] = s;
  }
  __syncthreads();
  // bc: 64 tokens x 32
  for (int idx = tid; idx < 64 * 32; idx += 256) {
    int t = idx >> 5, c = idx & 31;
    bc[(size_t)(bm0 + t) * 32 + c] = xps[t][1 + c];
  }
  // delta: thread covers channels c0..c0+7 for all 64 tokens
  {
    int c0 = tid * 8;
    float wv8[8], bv8[8];
    *(float4*)wv8       = ((const float4*)(dtw + c0))[0];
    *(float4*)(wv8 + 4) = ((const float4*)(dtw + c0))[1];
    *(float4*)bv8       = ((const float4*)(dtb + c0))[0];
    *(float4*)(bv8 + 4) = ((const float4*)(dtb + c0))[1];
    for (int t = 0; t < 64; t++) {
      float dr = xps[t][0];
      u16x8 o;
#pragma unroll
      for (int j = 0; j < 8; j++) o[j] = f2bf(softplus_f(dr * wv8[j] + bv8[j]));
      *(u16x8*)(dlt + (size_t)(bm0 + t) * DI_ + c0) = o;
    }
  }
}

// ============ segmented selective scan (4 states/lane, LDS-staged tiles) ============
#define SRT 72
#define SBC 36

__global__ __launch_bounds__(256) void scan_pass1(const float* __restrict__ bc,
    const u16* __restrict__ dlt, const u16* __restrict__ xc,
    const float* __restrict__ A_log, float* __restrict__ P, float* __restrict__ Q) {
  __shared__ __align__(16) u16 sD[LSEG * SRT];
  __shared__ __align__(16) u16 sX[LSEG * SRT];
  __shared__ __align__(16) float sB[LSEG * SBC];
  int tid = threadIdx.x;
  int lane = tid & 63, wv = tid >> 6;
  int nl = (lane & 3) * 4;
  int dl = wv * 16 + (lane >> 2);
  int d0 = blockIdx.x * 64;
  int s = blockIdx.y, b = blockIdx.z;
  int t0 = b * SEQ + s * LSEG;
  {
    int tr = tid >> 3, c = (tid & 7) * 8;
    *(u16x8*)&sD[tr * SRT + c] = *(const u16x8*)(dlt + (size_t)(t0 + tr) * DI_ + d0 + c);
    *(u16x8*)&sX[tr * SRT + c] = *(const u16x8*)(xc  + (size_t)(t0 + tr) * DI_ + d0 + c);
    int tb = tid & 31, cb = (tid >> 5) * 4;
    *(f32x4*)&sB[tb * SBC + cb] = *(const f32x4*)(bc + (size_t)(t0 + tb) * 32 + cb);
  }
  int d = d0 + dl;
  float4 Ain = *(const float4*)(A_log + d * DS_ + nl);
  f32x4 Av;
  Av[0] = -__expf(Ain.x); Av[1] = -__expf(Ain.y);
  Av[2] = -__expf(Ain.z); Av[3] = -__expf(Ain.w);
  f32x4 Pv, h;
#pragma unroll
  for (int i = 0; i < 4; i++) { Pv[i] = 1.f; h[i] = 0.f; }
  __syncthreads();
#pragma unroll 8
  for (int j = 0; j < LSEG; j++) {
    float delta = bf2f(sD[j * SRT + dl]);
    float xcv   = bf2f(sX[j * SRT + dl]);
    f32x4 B4 = *(const f32x4*)&sB[j * SBC + nl];
    float du = delta * xcv;
#pragma unroll
    for (int i = 0; i < 4; i++) {
      float a = __expf(delta * Av[i]);
      Pv[i] *= a;
      h[i] = fmaf(a, h[i], du * B4[i]);
    }
  }
  size_t idx = ((size_t)((b * NSEG + s) * DI_ + d)) * 16 + nl;
  *(f32x4*)(P + idx) = Pv;
  *(f32x4*)(Q + idx) = h;
}

// pass2 + fused prefix (combine) + gate: y = (p + xc*D) * silu(z)
__global__ __launch_bounds__(256) void scan_pass2(const float* __restrict__ bc,
    const u16* __restrict__ dlt, const u16* __restrict__ xz,
    const u16* __restrict__ xc,
    const float* __restrict__ A_log, const float* __restrict__ Dskip,
    const float* __restrict__ P, const float* __restrict__ Q,
    u16* __restrict__ yb) {
  __shared__ __align__(16) u16 sD[LSEG * SRT];
  __shared__ __align__(16) u16 sX[LSEG * SRT];
  __shared__ __align__(16) u16 sZ[LSEG * SRT];
  __shared__ __align__(16) float sB[LSEG * SBC];
  int tid = threadIdx.x;
  int lane = tid & 63, wv = tid >> 6;
  int nl = (lane & 3) * 4;
  int dl = wv * 16 + (lane >> 2);
  int d0 = blockIdx.x * 64;
  int s = blockIdx.y, b = blockIdx.z;
  int t0 = b * SEQ + s * LSEG;
  {
    int tr = tid >> 3, c = (tid & 7) * 8;
    *(u16x8*)&sD[tr * SRT + c] = *(const u16x8*)(dlt + (size_t)(t0 + tr) * DI_ + d0 + c);
    *(u16x8*)&sZ[tr * SRT + c] = *(const u16x8*)(xz + (size_t)(t0 + tr) * (2 * DI_) + DI_ + d0 + c);
    *(u16x8*)&sX[tr * SRT + c] = *(const u16x8*)(xc  + (size_t)(t0 + tr) * DI_ + d0 + c);
    int tb = tid & 31, cb = (tid >> 5) * 4;
    *(f32x4*)&sB[tb * SBC + cb] = *(const f32x4*)(bc + (size_t)(t0 + tb) * 32 + cb);
  }
  int d = d0 + dl;
  float4 Ain = *(const float4*)(A_log + d * DS_ + nl);
  f32x4 Av;
  Av[0] = -__expf(Ain.x); Av[1] = -__expf(Ain.y);
  Av[2] = -__expf(Ain.z); Av[3] = -__expf(Ain.w);
  float Dv = Dskip[d];
  // fused exclusive prefix over segments < s (identical fma order to old combine)
  f32x4 h;
#pragma unroll
  for (int i = 0; i < 4; i++) h[i] = 0.f;
  for (int s2 = 0; s2 < s; s2++) {
    size_t ix = ((size_t)((b * NSEG + s2) * DI_ + d)) * 16 + nl;
    f32x4 Pv = *(const f32x4*)(P + ix);
    f32x4 Qv = *(const f32x4*)(Q + ix);
#pragma unroll
    for (int i = 0; i < 4; i++) h[i] = fmaf(Pv[i], h[i], Qv[i]);
  }
  __syncthreads();
#pragma unroll 8
  for (int j = 0; j < LSEG; j++) {
    float delta = bf2f(sD[j * SRT + dl]);
    float xcv   = bf2f(sX[j * SRT + dl]);
    f32x4 B4 = *(const f32x4*)&sB[j * SBC + nl];
    f32x4 C4 = *(const f32x4*)&sB[j * SBC + 16 + nl];
    float du = delta * xcv;
#pragma unroll
    for (int i = 0; i < 4; i++) {
      float a = __expf(delta * Av[i]);
      h[i] = fmaf(a, h[i], du * B4[i]);
    }
    float p = h[0] * C4[0];
    p = fmaf(h[1], C4[1], p);
    p = fmaf(h[2], C4[2], p);
    p = fmaf(h[3], C4[3], p);
    p += __shfl_xor(p, 1);
    p += __shfl_xor(p, 2);
    if ((lane & 3) == 0) {
      float z = bf2f(sZ[j * SRT + dl]);
      float sz = z / (1.0f + __expf(-z));
      yb[(size_t)(t0 + j) * DI_ + d] = f2bf((p + xcv * Dv) * sz);
    }
  }
}

extern "C" void kernel_launch(void* const* d_in, const int* in_sizes, int n_in,
                              void* d_out, int out_size, void* d_ws, size_t ws_size,
                              hipStream_t stream) {
  const float* x      = (const float*)d_in[0];
  const float* norm_w = (const float*)d_in[1];
  const float* norm_b = (const float*)d_in[2];
  const float* in_w   = (const float*)d_in[3];
  const float* conv_w = (const float*)d_in[4];
  const float* conv_b = (const float*)d_in[5];
  const float* xproj_w= (const float*)d_in[6];
  const float* dt_w   = (const float*)d_in[7];
  const float* dt_b   = (const float*)d_in[8];
  const float* A_log  = (const float*)d_in[9];
  const float* D_skip = (const float*)d_in[10];
  const float* out_w  = (const float*)d_in[11];
  float* out = (float*)d_out;

  char* ws = (char*)d_ws;
  size_t off = 0;
  auto alloc = [&](size_t bytes) { void* p = ws + off; off += (bytes + 255) & ~255ULL; return p; };
  u16* in_w_bf  = (u16*)alloc((size_t)2 * DI_ * DIM_ * 2);
  u16* out_w_bf = (u16*)alloc((size_t)DIM_ * DI_ * 2);
  u16* xpw_bf   = (u16*)alloc((size_t)64 * DI_ * 2);
  u16* xn       = (u16*)alloc((size_t)NTOK * DIM_ * 2);
  u16* xz       = (u16*)alloc((size_t)NTOK * 2 * DI_ * 2);
  u16* xc       = (u16*)alloc((size_t)NTOK * DI_ * 2);
  u16* dlt      = (u16*)alloc((size_t)NTOK * DI_ * 2);
  float* bc     = (float*)alloc((size_t)NTOK * 32 * 4);
  float* xp_part= (float*)alloc((size_t)8 * NTOK * 64 * 4);
  float* P      = (float*)alloc((size_t)BATCH * NSEG * DI_ * 16 * 4);
  float* Q      = (float*)alloc((size_t)BATCH * NSEG * DI_ * 16 * 4);
  u16* yb       = (u16*)alloc((size_t)NTOK * DI_ * 2);
  unsigned int* cnt = (unsigned int*)alloc((size_t)(NTOK / 64) * 4);

  // 1: weight conversions + LN + counter zero
  cvt_ln_kernel<<<CVT_BLOCKS + NTOK, 256, 0, stream>>>(in_w, out_w, xproj_w, x,
                                                       norm_w, norm_b, in_w_bf,
                                                       out_w_bf, xpw_bf, xn, cnt);
  // 2: in_proj 128x128, BK=64, XCD-swizzled -> 512 blocks (reg-staged)
  gemm_bt<128, 128, 64, u16, 0, 1, 1><<<dim3((2 * DI_) / 128, NTOK / 128), 256, 0, stream>>>(
      xn, in_w_bf, xz, nullptr, NTOK, 2 * DI_, DIM_);
  // 3: FUSED conv+silu + x_proj split-K=8 + last-block finish (xp_finish removed)
  convxp_gemm<<<dim3(1, NTOK / 64, 8), 256, 0, stream>>>(
      xz, conv_w, conv_b, xpw_bf, xp_part, xc, dt_w, dt_b, bc, dlt, cnt);
  // 4: pass1 (LDS-staged)
  scan_pass1<<<dim3(DI_ / 64, NSEG, BATCH), 256, 0, stream>>>(bc, dlt, xc, A_log, P, Q);
  // 5: pass2 with fused cross-segment prefix
  scan_pass2<<<dim3(DI_ / 64, NSEG, BATCH), 256, 0, stream>>>(bc, dlt, xz, xc, A_log,
                                                              D_skip, P, Q, yb);
  // 6: out_proj 64x64, BK=64, EPI=1, XCD-swizzled -> 512 blocks (reg-staged)
  gemm_bt<64, 64, 64, float, 1, 1, 1><<<dim3(DIM_ / 64, NTOK / 64), 256, 0, stream>>>(
      yb, out_w_bf, out, x, NTOK, DIM_, DI_);
}

// Round 10
// 217.322 us; speedup vs baseline: 1.2104x; 1.2104x over previous
//
#include <hip/hip_runtime.h>
#include <stdint.h>

#define BATCH 2
#define SEQ   1024
#define DIM_  1024
#define DS_   16
#define DI_   2048
#define NTOK  (BATCH*SEQ)   // 2048
#define NSEG  32
#define LSEG  (SEQ/NSEG)    // 32

typedef unsigned short u16;
using s16x8 = __attribute__((ext_vector_type(8))) short;
using f32x4 = __attribute__((ext_vector_type(4))) float;
using u16x4 = __attribute__((ext_vector_type(4))) unsigned short;
using u16x8 = __attribute__((ext_vector_type(8))) unsigned short;

__device__ __forceinline__ float bf2f(u16 u) {
  union { unsigned int i; float f; } c; c.i = ((unsigned int)u) << 16; return c.f;
}
__device__ __forceinline__ u16 f2bf(float f) {
  union { float f; unsigned int i; } c; c.f = f;
  unsigned int r = c.i + 0x7fffu + ((c.i >> 16) & 1u);
  return (u16)(r >> 16);
}
__device__ __forceinline__ float softplus_f(float x) {
  return (x > 15.f) ? x : __logf(1.f + __expf(x));
}
__device__ __forceinline__ u16x4 f4_to_bf(float4 v) {
  u16x4 r; r[0] = f2bf(v.x); r[1] = f2bf(v.y); r[2] = f2bf(v.z); r[3] = f2bf(v.w);
  return r;
}

// ---------------- merged: weight conversions + LayerNorm ----------------
#define N4_INW  (2 * DI_ * DIM_ / 4)   // 1048576
#define N4_OUTW (DIM_ * DI_ / 4)       // 524288
#define CVT_BLOCKS ((N4_INW + N4_OUTW + 32768) / 256)   // 6272
__global__ __launch_bounds__(256) void cvt_ln_kernel(const float* __restrict__ in_w,
    const float* __restrict__ out_w, const float* __restrict__ xproj_w,
    const float* __restrict__ x, const float* __restrict__ nw,
    const float* __restrict__ nb, u16* __restrict__ in_w_bf,
    u16* __restrict__ out_w_bf, u16* __restrict__ xpw_bf, u16* __restrict__ xn) {
  int tid = threadIdx.x;
  if (blockIdx.x < CVT_BLOCKS) {
    int i = blockIdx.x * 256 + tid;
    if (i < N4_INW) {
      ((u16x4*)in_w_bf)[i] = f4_to_bf(((const float4*)in_w)[i]);
    } else if (i < N4_INW + N4_OUTW) {
      int j = i - N4_INW;
      ((u16x4*)out_w_bf)[j] = f4_to_bf(((const float4*)out_w)[j]);
    } else {
      int j = i - (N4_INW + N4_OUTW);
      if (j >= 32768) return;
      int p = (j * 4) >> 11;
      u16x4 r;
      if (p < 33) r = f4_to_bf(((const float4*)xproj_w)[j]);
      else { r[0] = 0; r[1] = 0; r[2] = 0; r[3] = 0; }
      ((u16x4*)xpw_bf)[j] = r;
    }
    return;
  }
  // LayerNorm branch
  int t = blockIdx.x - CVT_BLOCKS;
  const float* row = x + (size_t)t * DIM_;
  float4 v = ((const float4*)row)[tid];
  float f[4] = {v.x, v.y, v.z, v.w};
  float s = 0.f, sq = 0.f;
#pragma unroll
  for (int j = 0; j < 4; j++) { s += f[j]; sq += f[j] * f[j]; }
#pragma unroll
  for (int m = 1; m < 64; m <<= 1) { s += __shfl_xor(s, m); sq += __shfl_xor(sq, m); }
  __shared__ float rs_[4], rq_[4];
  int wv = tid >> 6;
  if ((tid & 63) == 0) { rs_[wv] = s; rq_[wv] = sq; }
  __syncthreads();
  s = rs_[0] + rs_[1] + rs_[2] + rs_[3];
  sq = rq_[0] + rq_[1] + rq_[2] + rq_[3];
  float mu = s * (1.0f / DIM_);
  float var = sq * (1.0f / DIM_) - mu * mu;
  float rstd = rsqrtf(var + 1e-5f);
  float4 wn = ((const float4*)nw)[tid];
  float4 bn = ((const float4*)nb)[tid];
  u16x4 o;
  o[0] = f2bf((f[0] - mu) * rstd * wn.x + bn.x);
  o[1] = f2bf((f[1] - mu) * rstd * wn.y + bn.y);
  o[2] = f2bf((f[2] - mu) * rstd * wn.z + bn.z);
  o[3] = f2bf((f[3] - mu) * rstd * wn.w + bn.w);
  *(u16x4*)(xn + (size_t)t * DIM_ + tid * 4) = o;
}

// ---------------- GEMM C = A(M,K)bf16 * W(N,K)^T bf16, f32 acc ----------------
template<int TBM, int TBN, int BK, typename OUT, int EPI, int KSPLIT = 1, int SWZ = 0>
__global__ __launch_bounds__(256) void gemm_bt(const u16* __restrict__ A,
    const u16* __restrict__ Wt, OUT* __restrict__ C, const float* __restrict__ X,
    int M, int N, int K) {
  constexpr int LDT = BK + 8;
  constexpr int TPR = BK / 8;
  constexpr int RPP = 256 / TPR;
  constexpr int ALn = TBM / RPP;
  constexpr int BLn = TBN / RPP;
  constexpr int KK = BK / 32;
  constexpr int WM = TBM / 2, WN = TBN / 2;
  constexpr int MI = WM / 16, NJ = WN / 16;
  __shared__ __align__(16) u16 sA[TBM * LDT];
  __shared__ __align__(16) u16 sB[TBN * LDT];
  const int tid = threadIdx.x;
  const int lane = tid & 63, wv = tid >> 6;
  const int wm = (wv >> 1) * WM, wn = (wv & 1) * WN;
  const int bxl = SWZ ? ((blockIdx.x & 7) * (gridDim.x >> 3) + (blockIdx.x >> 3))
                      : blockIdx.x;
  const int bm0 = blockIdx.y * TBM, bn0 = bxl * TBN;
  const int q = lane >> 4, r16 = lane & 15;
  const int srow = tid / TPR, scol = (tid % TPR) * 8;
  const int kc = K / KSPLIT;
  const int k0 = (KSPLIT > 1) ? blockIdx.z * kc : 0;
  const int kend = k0 + kc;

  f32x4 acc[MI][NJ];
#pragma unroll
  for (int i = 0; i < MI; i++)
#pragma unroll
    for (int j = 0; j < NJ; j++)
#pragma unroll
      for (int r = 0; r < 4; r++) acc[i][j][r] = 0.f;

  const u16* Ag = A + (size_t)bm0 * K + scol + k0;
  const u16* Wg = Wt + (size_t)bn0 * K + scol + k0;
  s16x8 ra[ALn], rb[BLn];
#pragma unroll
  for (int i = 0; i < ALn; i++) ra[i] = *(const s16x8*)(Ag + (size_t)(srow + i * RPP) * K);
#pragma unroll
  for (int i = 0; i < BLn; i++) rb[i] = *(const s16x8*)(Wg + (size_t)(srow + i * RPP) * K);

  for (int kt = k0; kt < kend; kt += BK) {
    __syncthreads();
#pragma unroll
    for (int i = 0; i < ALn; i++) *(s16x8*)&sA[(srow + i * RPP) * LDT + scol] = ra[i];
#pragma unroll
    for (int i = 0; i < BLn; i++) *(s16x8*)&sB[(srow + i * RPP) * LDT + scol] = rb[i];
    __syncthreads();
    int kn = kt + BK - k0;
    if (kn < kc) {
#pragma unroll
      for (int i = 0; i < ALn; i++) ra[i] = *(const s16x8*)(Ag + (size_t)(srow + i * RPP) * K + kn);
#pragma unroll
      for (int i = 0; i < BLn; i++) rb[i] = *(const s16x8*)(Wg + (size_t)(srow + i * RPP) * K + kn);
    }
#pragma unroll
    for (int kk = 0; kk < KK; kk++) {
      s16x8 fa[MI], fb[NJ];
#pragma unroll
      for (int i = 0; i < MI; i++)
        fa[i] = *(const s16x8*)&sA[(wm + i * 16 + r16) * LDT + kk * 32 + q * 8];
#pragma unroll
      for (int j = 0; j < NJ; j++)
        fb[j] = *(const s16x8*)&sB[(wn + j * 16 + r16) * LDT + kk * 32 + q * 8];
#pragma unroll
      for (int i = 0; i < MI; i++)
#pragma unroll
        for (int j = 0; j < NJ; j++)
          acc[i][j] = __builtin_amdgcn_mfma_f32_16x16x32_bf16(fa[i], fb[j], acc[i][j], 0, 0, 0);
    }
  }
  OUT* Cz = C + ((KSPLIT > 1) ? (size_t)blockIdx.z * M * N : 0);
#pragma unroll
  for (int i = 0; i < MI; i++)
#pragma unroll
    for (int j = 0; j < NJ; j++) {
      int row0 = bm0 + wm + i * 16 + q * 4;
      int col = bn0 + wn + j * 16 + r16;
#pragma unroll
      for (int r = 0; r < 4; r++) {
        size_t off = (size_t)(row0 + r) * N + col;
        float v = acc[i][j][r];
        if constexpr (EPI == 1) v += X[off];
        if constexpr (sizeof(OUT) == 2) Cz[off] = f2bf(v);
        else                            Cz[off] = v;
      }
    }
}

// ---------------- fused conv+silu + x_proj split-K GEMM (R8 exact, no fences) ----------------
__global__ __launch_bounds__(256) void convxp_gemm(const u16* __restrict__ xz,
    const float* __restrict__ cw, const float* __restrict__ cb,
    const u16* __restrict__ Wt, float* __restrict__ C, u16* __restrict__ xc) {
  constexpr int BK = 32, LDT = BK + 8;
  constexpr int WM = 32, WN = 32, MI = 2, NJ = 2;
  constexpr int K = DI_, Nn = 64;
  __shared__ __align__(16) u16 sA[64 * LDT];
  __shared__ __align__(16) u16 sB[64 * LDT];
  const int tid = threadIdx.x;
  const int lane = tid & 63, wv = tid >> 6;
  const int wm = (wv >> 1) * WM, wn = (wv & 1) * WN;
  const int bm0 = blockIdx.y * 64;
  const int q = lane >> 4, r16 = lane & 15;
  const int srow = tid >> 2, scol = (tid & 3) * 8;   // TPR=4, RPP=64
  const int kc = K / 8;
  const int k0 = blockIdx.z * kc;

  f32x4 acc[MI][NJ];
#pragma unroll
  for (int i = 0; i < MI; i++)
#pragma unroll
    for (int j = 0; j < NJ; j++)
#pragma unroll
      for (int r = 0; r < 4; r++) acc[i][j][r] = 0.f;

  const int tm = bm0 + srow;
  const int l = tm & (SEQ - 1);
  const u16* Wg = Wt + (size_t)srow * K + scol + k0;

  auto conv8 = [&](int kt) -> s16x8 {
    int ch = k0 + kt + scol;
    float a[8];
    float4 cb0 = *(const float4*)(cb + ch);
    float4 cb1 = *(const float4*)(cb + ch + 4);
    a[0] = cb0.x; a[1] = cb0.y; a[2] = cb0.z; a[3] = cb0.w;
    a[4] = cb1.x; a[5] = cb1.y; a[6] = cb1.z; a[7] = cb1.w;
#pragma unroll
    for (int k = 0; k < 4; k++) {
      if (l - 3 + k >= 0) {
        u16x8 v = *(const u16x8*)(xz + (size_t)(tm - 3 + k) * (2 * DI_) + ch);
#pragma unroll
        for (int j = 0; j < 8; j++) {
          float4 wj = ((const float4*)cw)[ch + j];
          float wk = (k == 0) ? wj.x : (k == 1) ? wj.y : (k == 2) ? wj.z : wj.w;
          a[j] = fmaf(bf2f(v[j]), wk, a[j]);
        }
      }
    }
    u16x8 o;
#pragma unroll
    for (int j = 0; j < 8; j++) {
      float s = a[j] / (1.0f + __expf(-a[j]));
      o[j] = f2bf(s);
    }
    *(u16x8*)(xc + (size_t)tm * DI_ + ch) = o;
    return *(s16x8*)&o;
  };

  s16x8 ra = conv8(0);
  s16x8 rb = *(const s16x8*)Wg;

  for (int kt = 0; kt < kc; kt += BK) {
    __syncthreads();
    *(s16x8*)&sA[srow * LDT + scol] = ra;
    *(s16x8*)&sB[srow * LDT + scol] = rb;
    __syncthreads();
    int kn = kt + BK;
    if (kn < kc) {
      ra = conv8(kn);
      rb = *(const s16x8*)(Wg + kn);
    }
    {
      s16x8 fa[MI], fb[NJ];
#pragma unroll
      for (int i = 0; i < MI; i++)
        fa[i] = *(const s16x8*)&sA[(wm + i * 16 + r16) * LDT + q * 8];
#pragma unroll
      for (int j = 0; j < NJ; j++)
        fb[j] = *(const s16x8*)&sB[(wn + j * 16 + r16) * LDT + q * 8];
#pragma unroll
      for (int i = 0; i < MI; i++)
#pragma unroll
        for (int j = 0; j < NJ; j++)
          acc[i][j] = __builtin_amdgcn_mfma_f32_16x16x32_bf16(fa[i], fb[j], acc[i][j], 0, 0, 0);
    }
  }
  float* Cz = C + (size_t)blockIdx.z * NTOK * Nn;
#pragma unroll
  for (int i = 0; i < MI; i++)
#pragma unroll
    for (int j = 0; j < NJ; j++) {
      int row0 = bm0 + wm + i * 16 + q * 4;
      int col = wn + j * 16 + r16;
#pragma unroll
      for (int r = 0; r < 4; r++)
        Cz[(size_t)(row0 + r) * Nn + col] = acc[i][j][r];
    }
}

// ============ scan pass1 + fused xp-finish (stream-ordered, no fences) ============
// Each block owns (64 channels, 32 tokens): reduces xp_part cols 0..32 for its
// tokens (L2-resident), computes delta for ITS channels (exactly once across the
// grid), writes delta -> xz delta-slot (for pass2) and bc (blockIdx.x==0 plane only).
#define SRT 72
#define XPS 36   // B/C cols 0..31 live at [t][0..31]; stride 144B (16B-aligned rows)

__global__ __launch_bounds__(256) void scan_pass1(const float* __restrict__ part,
    const float* __restrict__ dtw, const float* __restrict__ dtb,
    u16* __restrict__ xz, const u16* __restrict__ xc,
    const float* __restrict__ A_log, float* __restrict__ bc,
    float* __restrict__ P, float* __restrict__ Q) {
  __shared__ __align__(16) u16 sD[LSEG * SRT];
  __shared__ __align__(16) u16 sX[LSEG * SRT];
  __shared__ __align__(16) float xps[LSEG][XPS];
  __shared__ float sDr[LSEG];
  int tid = threadIdx.x;
  int lane = tid & 63, wv = tid >> 6;
  int nl = (lane & 3) * 4;
  int dl = wv * 16 + (lane >> 2);
  int d0 = blockIdx.x * 64;
  int s = blockIdx.y, b = blockIdx.z;
  int t0 = b * SEQ + s * LSEG;
  // ---- phase A: stage xc + parallel reduce of xp_part cols 0..32 ----
  {
    int tr = tid >> 3, c = (tid & 7) * 8;
    *(u16x8*)&sX[tr * SRT + c] = *(const u16x8*)(xc + (size_t)(t0 + tr) * DI_ + d0 + c);
    for (int it = tid; it < LSEG * 33; it += 256) {
      int t = it / 33, c2 = it - t * 33;
      float sum = 0.f;
#pragma unroll
      for (int k = 0; k < 8; k++)
        sum += part[(size_t)k * NTOK * 64 + (size_t)(t0 + t) * 64 + c2];
      if (c2 == 0) sDr[t] = sum;
      else         xps[t][c2 - 1] = sum;
    }
  }
  __syncthreads();
  // ---- phase B: delta for OUR 64 channels -> sD + xz delta-slot; bc (bx==0) ----
  {
    int t = tid >> 3, c0 = (tid & 7) * 8;
    float dr = sDr[t];
    float w8[8], b8[8];
    *(float4*)w8       = *(const float4*)(dtw + d0 + c0);
    *(float4*)(w8 + 4) = *(const float4*)(dtw + d0 + c0 + 4);
    *(float4*)b8       = *(const float4*)(dtb + d0 + c0);
    *(float4*)(b8 + 4) = *(const float4*)(dtb + d0 + c0 + 4);
    u16x8 o;
#pragma unroll
    for (int j = 0; j < 8; j++) o[j] = f2bf(softplus_f(dr * w8[j] + b8[j]));
    *(u16x8*)&sD[t * SRT + c0] = o;
    *(u16x8*)(xz + (size_t)(t0 + t) * (2 * DI_) + d0 + c0) = o;
    if (blockIdx.x == 0) {
      for (int it = tid; it < LSEG * 32; it += 256) {
        int tt = it >> 5, cc = it & 31;
        bc[(size_t)(t0 + tt) * 32 + cc] = xps[tt][cc];
      }
    }
  }
  int d = d0 + dl;
  float4 Ain = *(const float4*)(A_log + d * DS_ + nl);
  f32x4 Av;
  Av[0] = -__expf(Ain.x); Av[1] = -__expf(Ain.y);
  Av[2] = -__expf(Ain.z); Av[3] = -__expf(Ain.w);
  f32x4 Pv, h;
#pragma unroll
  for (int i = 0; i < 4; i++) { Pv[i] = 1.f; h[i] = 0.f; }
  __syncthreads();
  // ---- phase C: local scan (delta from sD, B from xps) ----
#pragma unroll 8
  for (int j = 0; j < LSEG; j++) {
    float delta = bf2f(sD[j * SRT + dl]);
    float xcv   = bf2f(sX[j * SRT + dl]);
    f32x4 B4 = *(const f32x4*)&xps[j][nl];
    float du = delta * xcv;
#pragma unroll
    for (int i = 0; i < 4; i++) {
      float a = __expf(delta * Av[i]);
      Pv[i] *= a;
      h[i] = fmaf(a, h[i], du * B4[i]);
    }
  }
  size_t idx = ((size_t)((b * NSEG + s) * DI_ + d)) * 16 + nl;
  *(f32x4*)(P + idx) = Pv;
  *(f32x4*)(Q + idx) = h;
}

// pass2 + fused prefix + gate (R8 exact): y = (p + xc*D) * silu(z)
#define SBC 36
__global__ __launch_bounds__(256) void scan_pass2(const float* __restrict__ bc,
    const u16* __restrict__ dlt, const u16* __restrict__ xc,
    const float* __restrict__ A_log, const float* __restrict__ Dskip,
    const float* __restrict__ P, const float* __restrict__ Q,
    u16* __restrict__ yb) {
  __shared__ __align__(16) u16 sD[LSEG * SRT];
  __shared__ __align__(16) u16 sX[LSEG * SRT];
  __shared__ __align__(16) u16 sZ[LSEG * SRT];
  __shared__ __align__(16) float sB[LSEG * SBC];
  int tid = threadIdx.x;
  int lane = tid & 63, wv = tid >> 6;
  int nl = (lane & 3) * 4;
  int dl = wv * 16 + (lane >> 2);
  int d0 = blockIdx.x * 64;
  int s = blockIdx.y, b = blockIdx.z;
  int t0 = b * SEQ + s * LSEG;
  {
    int tr = tid >> 3, c = (tid & 7) * 8;
    *(u16x8*)&sD[tr * SRT + c] = *(const u16x8*)(dlt + (size_t)(t0 + tr) * (2 * DI_) + d0 + c);
    *(u16x8*)&sZ[tr * SRT + c] = *(const u16x8*)(dlt + (size_t)(t0 + tr) * (2 * DI_) + DI_ + d0 + c);
    *(u16x8*)&sX[tr * SRT + c] = *(const u16x8*)(xc  + (size_t)(t0 + tr) * DI_ + d0 + c);
    int tb = tid & 31, cb = (tid >> 5) * 4;
    *(f32x4*)&sB[tb * SBC + cb] = *(const f32x4*)(bc + (size_t)(t0 + tb) * 32 + cb);
  }
  int d = d0 + dl;
  float4 Ain = *(const float4*)(A_log + d * DS_ + nl);
  f32x4 Av;
  Av[0] = -__expf(Ain.x); Av[1] = -__expf(Ain.y);
  Av[2] = -__expf(Ain.z); Av[3] = -__expf(Ain.w);
  float Dv = Dskip[d];
  // fused exclusive prefix over segments < s
  f32x4 h;
#pragma unroll
  for (int i = 0; i < 4; i++) h[i] = 0.f;
  for (int s2 = 0; s2 < s; s2++) {
    size_t ix = ((size_t)((b * NSEG + s2) * DI_ + d)) * 16 + nl;
    f32x4 Pv = *(const f32x4*)(P + ix);
    f32x4 Qv = *(const f32x4*)(Q + ix);
#pragma unroll
    for (int i = 0; i < 4; i++) h[i] = fmaf(Pv[i], h[i], Qv[i]);
  }
  __syncthreads();
#pragma unroll 8
  for (int j = 0; j < LSEG; j++) {
    float delta = bf2f(sD[j * SRT + dl]);
    float xcv   = bf2f(sX[j * SRT + dl]);
    f32x4 B4 = *(const f32x4*)&sB[j * SBC + nl];
    f32x4 C4 = *(const f32x4*)&sB[j * SBC + 16 + nl];
    float du = delta * xcv;
#pragma unroll
    for (int i = 0; i < 4; i++) {
      float a = __expf(delta * Av[i]);
      h[i] = fmaf(a, h[i], du * B4[i]);
    }
    float p = h[0] * C4[0];
    p = fmaf(h[1], C4[1], p);
    p = fmaf(h[2], C4[2], p);
    p = fmaf(h[3], C4[3], p);
    p += __shfl_xor(p, 1);
    p += __shfl_xor(p, 2);
    if ((lane & 3) == 0) {
      float z = bf2f(sZ[j * SRT + dl]);
      float sz = z / (1.0f + __expf(-z));
      yb[(size_t)(t0 + j) * DI_ + d] = f2bf((p + xcv * Dv) * sz);
    }
  }
}

extern "C" void kernel_launch(void* const* d_in, const int* in_sizes, int n_in,
                              void* d_out, int out_size, void* d_ws, size_t ws_size,
                              hipStream_t stream) {
  const float* x      = (const float*)d_in[0];
  const float* norm_w = (const float*)d_in[1];
  const float* norm_b = (const float*)d_in[2];
  const float* in_w   = (const float*)d_in[3];
  const float* conv_w = (const float*)d_in[4];
  const float* conv_b = (const float*)d_in[5];
  const float* xproj_w= (const float*)d_in[6];
  const float* dt_w   = (const float*)d_in[7];
  const float* dt_b   = (const float*)d_in[8];
  const float* A_log  = (const float*)d_in[9];
  const float* D_skip = (const float*)d_in[10];
  const float* out_w  = (const float*)d_in[11];
  float* out = (float*)d_out;

  char* ws = (char*)d_ws;
  size_t off = 0;
  auto alloc = [&](size_t bytes) { void* p = ws + off; off += (bytes + 255) & ~255ULL; return p; };
  u16* in_w_bf  = (u16*)alloc((size_t)2 * DI_ * DIM_ * 2);
  u16* out_w_bf = (u16*)alloc((size_t)DIM_ * DI_ * 2);
  u16* xpw_bf   = (u16*)alloc((size_t)64 * DI_ * 2);
  u16* xn       = (u16*)alloc((size_t)NTOK * DIM_ * 2);
  u16* xz       = (u16*)alloc((size_t)NTOK * 2 * DI_ * 2);
  u16* xc       = (u16*)alloc((size_t)NTOK * DI_ * 2);
  float* bc     = (float*)alloc((size_t)NTOK * 32 * 4);
  float* xp_part= (float*)alloc((size_t)8 * NTOK * 64 * 4);
  float* P      = (float*)alloc((size_t)BATCH * NSEG * DI_ * 16 * 4);
  float* Q      = (float*)alloc((size_t)BATCH * NSEG * DI_ * 16 * 4);
  u16* yb       = (u16*)alloc((size_t)NTOK * DI_ * 2);

  // 1: weight conversions + LN
  cvt_ln_kernel<<<CVT_BLOCKS + NTOK, 256, 0, stream>>>(in_w, out_w, xproj_w, x,
                                                       norm_w, norm_b, in_w_bf,
                                                       out_w_bf, xpw_bf, xn);
  // 2: in_proj 128x128, BK=64, XCD-swizzled -> 512 blocks (reg-staged)
  gemm_bt<128, 128, 64, u16, 0, 1, 1><<<dim3((2 * DI_) / 128, NTOK / 128), 256, 0, stream>>>(
      xn, in_w_bf, xz, nullptr, NTOK, 2 * DI_, DIM_);
  // 3: FUSED conv+silu + x_proj split-K=8 -> 256 blocks
  convxp_gemm<<<dim3(1, NTOK / 64, 8), 256, 0, stream>>>(
      xz, conv_w, conv_b, xpw_bf, xp_part, xc);
  // 4: pass1 + fused xp-finish (delta->xz slot, bc by bx==0 plane; xp_finish removed)
  scan_pass1<<<dim3(DI_ / 64, NSEG, BATCH), 256, 0, stream>>>(
      xp_part, dt_w, dt_b, xz, xc, A_log, bc, P, Q);
  // 5: pass2 with fused cross-segment prefix (reads delta/z from xz, bc from pass1)
  scan_pass2<<<dim3(DI_ / 64, NSEG, BATCH), 256, 0, stream>>>(bc, xz, xc, A_log,
                                                              D_skip, P, Q, yb);
  // 6: out_proj 64x64, BK=64, EPI=1, XCD-swizzled -> 512 blocks (reg-staged)
  gemm_bt<64, 64, 64, float, 1, 1, 1><<<dim3(DIM_ / 64, NTOK / 64), 256, 0, stream>>>(
      yb, out_w_bf, out, x, NTOK, DIM_, DI_);
}